// Round 2
// baseline (676.687 us; speedup 1.0000x reference)
//
#include <hip/hip_runtime.h>
#include <math.h>

#define NN 10000
#define NE 640000
#define H 128
#define H2 256
#define XD 8
#define ED 8
#define YD 112
#define NL 4
#define EPS_MSG 1e-7f
#define EPS_SM 1e-16f
#define EPS_LN 1e-5f
#define TN 16
#define EB 64
#define PB 16

// ---------- CSR build ----------
__global__ void hist_k(const int* __restrict__ dst, int* __restrict__ counts) {
    int e = blockIdx.x * 256 + threadIdx.x;
    if (e < NE) atomicAdd(&counts[dst[e]], 1);
}

__global__ void scan_k(const int* __restrict__ counts, int* __restrict__ rowptr) {
    __shared__ int part[1024];
    int tid = threadIdx.x;
    const int CH = (NN + 1023) / 1024;  // 10
    int base = tid * CH;
    int s = 0;
    for (int j = 0; j < CH; j++) { int i = base + j; if (i < NN) s += counts[i]; }
    part[tid] = s; __syncthreads();
    for (int off = 1; off < 1024; off <<= 1) {
        int v = (tid >= off) ? part[tid - off] : 0;
        __syncthreads();
        part[tid] += v;
        __syncthreads();
    }
    int run = part[tid] - s;  // exclusive prefix
    for (int j = 0; j < CH; j++) {
        int i = base + j;
        if (i < NN) { rowptr[i] = run; run += counts[i]; }
    }
    if (tid == 1023) rowptr[NN] = run;  // == NE
}

__global__ void scatter_k(const int* __restrict__ src, const int* __restrict__ dst,
                          const int* __restrict__ rowptr, int* __restrict__ fill,
                          int2* __restrict__ se) {
    int e = blockIdx.x * 256 + threadIdx.x;
    if (e >= NE) return;
    int d = dst[e];
    int pos = rowptr[d] + atomicAdd(&fill[d], 1);
    se[pos] = make_int2(src[e], e);
}

// ---------- edge projection, once: ea[pos][c] = eattr[perm[pos]] . We[:,c] + be[c] ----------
__global__ void __launch_bounds__(256) proj_k(const float* __restrict__ eattr,
    const int2* __restrict__ se, const float* __restrict__ We,
    const float* __restrict__ be, _Float16* __restrict__ ea_s) {
    int p0 = blockIdx.x * PB;
    int t = threadIdx.x;  // 256
    __shared__ float ar[PB][ED];
    if (t < PB * ED) {
        int pl = t / ED, k = t % ED;
        int e = se[p0 + pl].y;
        ar[pl][k] = eattr[(size_t)e * ED + k];
    }
    __syncthreads();
    int c = t & 127, ph = t >> 7;  // ph in {0,1}
    float wcol[ED];
#pragma unroll
    for (int k = 0; k < ED; k++) wcol[k] = We[k * H + c];
    float bec = be[c];
    for (int pl = ph; pl < PB; pl += 2) {
        float a = bec;
#pragma unroll
        for (int k = 0; k < ED; k++) a = fmaf(ar[pl][k], wcol[k], a);
        ea_s[(size_t)(p0 + pl) * H + c] = (_Float16)a;
    }
}

// ---------- node encoder: h = x @ Wn + bn ----------
__global__ void node_enc_k(const float* __restrict__ x, const float* __restrict__ Wn,
                           const float* __restrict__ bn, float* __restrict__ h) {
    int n = blockIdx.x, c = threadIdx.x;
    __shared__ float xl[XD];
    if (c < XD) xl[c] = x[n * XD + c];
    __syncthreads();
    float acc = bn[c];
#pragma unroll
    for (int k = 0; k < XD; k++) acc = fmaf(xl[k], Wn[k * H + c], acc);
    h[(size_t)n * H + c] = acc;
}

// ---------- per-node edge aggregation, segment-softmax (M=0: logits bounded) ----------
__global__ void __launch_bounds__(128) edge_agg_k(
    const float* __restrict__ rin, const int* __restrict__ rowptr,
    const int2* __restrict__ se, const _Float16* __restrict__ ea_s,
    const float* __restrict__ tptr, int layer, float* __restrict__ agg) {
    int n = blockIdx.x, c = threadIdx.x;
    int beg = rowptr[n], end = rowptr[n + 1];
    float ts2 = tptr[layer] * 1.44269504088896f;  // t * log2(e)
    float den = 0.f, num = 0.f;
    __shared__ int ebS[EB];
    for (int j0 = beg; j0 < end; j0 += EB) {
        int cnt = min(EB, end - j0);
        __syncthreads();
        if (c < cnt) ebS[c] = se[j0 + c].x;
        __syncthreads();
        const _Float16* ep = ea_s + (size_t)j0 * H + c;
#pragma unroll 2
        for (int j = 0; j < cnt; ++j) {
            int sn = ebS[j];
            float ea = (float)ep[(size_t)j * H];
            float hv = rin[(size_t)sn * H + c];
            float msg = fmaxf(hv + ea, 0.f) + EPS_MSG;
            float p = __builtin_amdgcn_exp2f(msg * ts2);
            den += p;
            num = fmaf(p, msg, num);
        }
    }
    agg[(size_t)n * H + c] = num / (den + EPS_SM) + rin[(size_t)n * H + c];
}

// ---------- y1 = agg @ W1[i] + b1[i], plus deterministic partial sums ----------
__global__ void __launch_bounds__(256) mm1_k(const float* __restrict__ agg,
    const float* __restrict__ W1i, const float* __restrict__ b1i,
    float* __restrict__ y1, float* __restrict__ part) {
    int nb = blockIdx.x, o = threadIdx.x;
    int n0 = nb * TN;
    __shared__ float a[TN][H];
    for (int t = o; t < TN * H; t += 256) ((float*)a)[t] = agg[(size_t)n0 * H + t];
    __syncthreads();
    float acc[TN];
#pragma unroll
    for (int i = 0; i < TN; i++) acc[i] = 0.f;
    for (int k = 0; k < H; k++) {
        float w = W1i[k * H2 + o];
#pragma unroll
        for (int i = 0; i < TN; i++) acc[i] = fmaf(a[i][k], w, acc[i]);
    }
    float bo = b1i[o];
    float ps = 0.f, ps2 = 0.f;
#pragma unroll
    for (int i = 0; i < TN; i++) {
        float v = acc[i] + bo;
        y1[(size_t)(n0 + i) * H2 + o] = v;
        ps += v; ps2 += v * v;
    }
#pragma unroll
    for (int off = 32; off; off >>= 1) { ps += __shfl_xor(ps, off); ps2 += __shfl_xor(ps2, off); }
    __shared__ float red[8];
    int w = o >> 6;
    if ((o & 63) == 0) { red[w] = ps; red[4 + w] = ps2; }
    __syncthreads();
    if (o == 0) {
        part[nb * 2]     = red[0] + red[1] + red[2] + red[3];
        part[nb * 2 + 1] = red[4] + red[5] + red[6] + red[7];
    }
}

// ---------- graph-LN stats finalize ----------
__global__ void stats_k(const float* __restrict__ part, int nb, float* __restrict__ stats) {
    int tid = threadIdx.x;  // 256
    float s = 0.f, s2 = 0.f;
    for (int i = tid; i < nb; i += 256) { s += part[2 * i]; s2 += part[2 * i + 1]; }
#pragma unroll
    for (int off = 32; off; off >>= 1) { s += __shfl_xor(s, off); s2 += __shfl_xor(s2, off); }
    __shared__ float red[8];
    int w = tid >> 6;
    if ((tid & 63) == 0) { red[w] = s; red[4 + w] = s2; }
    __syncthreads();
    if (tid == 0) {
        float S = red[0] + red[1] + red[2] + red[3];
        float S2 = red[4] + red[5] + red[6] + red[7];
        const float M = (float)NN * (float)H2;
        float m = S / M;
        float var = fmaxf(S2 / M - m * m, 0.f);
        stats[0] = m;
        stats[1] = 1.f / (sqrtf(var) + EPS_LN);
    }
}

// ---------- z = relu(graph_ln(y1)); h (+)= z @ W2[i] + b2[i]; r = relu(node_ln(h)) ----------
__global__ void __launch_bounds__(128) mm2_k(const float* __restrict__ y1,
    const float* __restrict__ g1i, const float* __restrict__ bt1i,
    const float* __restrict__ W2i, const float* __restrict__ b2i,
    const float* __restrict__ stats, float* __restrict__ h,
    const float* __restrict__ lgp, const float* __restrict__ lbp,
    float* __restrict__ r, int first) {
    int nb = blockIdx.x, o = threadIdx.x;
    int n0 = nb * TN;
    __shared__ float z[TN][H2];  // 16 KiB
    float m = stats[0], istd = stats[1];
    for (int t = o; t < TN * H2; t += 128) {
        int k = t & 255;
        float v = y1[(size_t)n0 * H2 + t];
        v = (v - m) * istd * g1i[k] + bt1i[k];
        ((float*)z)[t] = fmaxf(v, 0.f);
    }
    __syncthreads();
    float acc[TN];
#pragma unroll
    for (int i = 0; i < TN; i++) acc[i] = 0.f;
    for (int k = 0; k < H2; k++) {
        float w = W2i[k * H + o];
#pragma unroll
        for (int i = 0; i < TN; i++) acc[i] = fmaf(z[i][k], w, acc[i]);
    }
    float bo = b2i[o];
    float vv[TN];
#pragma unroll
    for (int i = 0; i < TN; i++) {
        size_t idx = (size_t)(n0 + i) * H + o;
        float v = acc[i] + bo;
        if (!first) v += h[idx];
        h[idx] = v;
        vv[i] = v;
    }
    // fused node-LN + ReLU -> r
    __shared__ float rs[2][TN], rs2[2][TN];
    int w = o >> 6;
#pragma unroll
    for (int i = 0; i < TN; i++) {
        float s = vv[i], s2 = vv[i] * vv[i];
#pragma unroll
        for (int off = 32; off; off >>= 1) { s += __shfl_xor(s, off); s2 += __shfl_xor(s2, off); }
        if ((o & 63) == 0) { rs[w][i] = s; rs2[w][i] = s2; }
    }
    __syncthreads();
    float gc = lgp[o], bc = lbp[o];
#pragma unroll
    for (int i = 0; i < TN; i++) {
        float S = rs[0][i] + rs[1][i], S2 = rs2[0][i] + rs2[1][i];
        float mn = S * (1.f / H);
        float var = S2 * (1.f / H) - mn * mn;
        float inv = rsqrtf(var + EPS_LN);
        float ov = (vv[i] - mn) * inv * gc + bc;
        r[(size_t)(n0 + i) * H + o] = fmaxf(ov, 0.f);
    }
}

// ---------- out = r @ Wout + bout ----------
__global__ void __launch_bounds__(128) mmout_k(const float* __restrict__ r,
    const float* __restrict__ Wout, const float* __restrict__ bout,
    float* __restrict__ out) {
    int nb = blockIdx.x, o = threadIdx.x;
    int n0 = nb * TN;
    __shared__ float a[TN][H];
    for (int t = o; t < TN * H; t += 128) ((float*)a)[t] = r[(size_t)n0 * H + t];
    __syncthreads();
    if (o < YD) {
        float acc[TN];
#pragma unroll
        for (int i = 0; i < TN; i++) acc[i] = 0.f;
        for (int k = 0; k < H; k++) {
            float w = Wout[k * YD + o];
#pragma unroll
            for (int i = 0; i < TN; i++) acc[i] = fmaf(a[i][k], w, acc[i]);
        }
        float bo = bout[o];
#pragma unroll
        for (int i = 0; i < TN; i++) out[(size_t)(n0 + i) * YD + o] = acc[i] + bo;
    }
}

extern "C" void kernel_launch(void* const* d_in, const int* in_sizes, int n_in,
                              void* d_out, int out_size, void* d_ws, size_t ws_size,
                              hipStream_t stream) {
    const float* x    = (const float*)d_in[0];
    const int*   ei   = (const int*)d_in[1];
    const float* eattr= (const float*)d_in[2];
    const float* Wn   = (const float*)d_in[3];
    const float* bn   = (const float*)d_in[4];
    const float* We   = (const float*)d_in[5];
    const float* be   = (const float*)d_in[6];
    const float* t    = (const float*)d_in[7];
    const float* W1   = (const float*)d_in[8];
    const float* b1   = (const float*)d_in[9];
    const float* g1   = (const float*)d_in[10];
    const float* bt1  = (const float*)d_in[11];
    const float* W2   = (const float*)d_in[12];
    const float* b2   = (const float*)d_in[13];
    const float* lng  = (const float*)d_in[14];
    const float* lnb  = (const float*)d_in[15];
    const float* Wout = (const float*)d_in[16];
    const float* bout = (const float*)d_in[17];
    float* out = (float*)d_out;

    const int* src = ei;        // edge_index[0]
    const int* dst = ei + NE;   // edge_index[1]

    char* ws = (char*)d_ws;
    size_t off = 0;
    auto alloc = [&](size_t bytes) -> char* {
        char* p = ws + off;
        off += (bytes + 255) & ~(size_t)255;
        return p;
    };
    int*      counts = (int*)alloc((size_t)NN * 4);
    int*      fill   = (int*)alloc((size_t)NN * 4);
    int*      rowptr = (int*)alloc((size_t)(NN + 1) * 4);
    int2*     se     = (int2*)alloc((size_t)NE * 8);
    _Float16* ea_s   = (_Float16*)alloc((size_t)NE * H * 2);  // 164 MB
    float*    h      = (float*)alloc((size_t)NN * H * 4);
    float*    r      = (float*)alloc((size_t)NN * H * 4);
    float*    agg    = (float*)alloc((size_t)NN * H * 4);
    float*    y1     = (float*)alloc((size_t)NN * H2 * 4);
    const int NB1 = NN / TN;  // 625 (exact)
    float*    part   = (float*)alloc((size_t)NB1 * 2 * 4);
    float*    stats  = (float*)alloc(2 * 4);
    (void)ws_size; (void)in_sizes; (void)n_in; (void)out_size;

    hipMemsetAsync(counts, 0, (size_t)NN * 4, stream);
    hipMemsetAsync(fill,   0, (size_t)NN * 4, stream);

    hist_k<<<(NE + 255) / 256, 256, 0, stream>>>(dst, counts);
    scan_k<<<1, 1024, 0, stream>>>(counts, rowptr);
    scatter_k<<<(NE + 255) / 256, 256, 0, stream>>>(src, dst, rowptr, fill, se);
    proj_k<<<NE / PB, 256, 0, stream>>>(eattr, se, We, be, ea_s);
    node_enc_k<<<NN, H, 0, stream>>>(x, Wn, bn, h);

    for (int i = 0; i < NL; i++) {
        const float* cin = (i == 0) ? h : r;
        edge_agg_k<<<NN, H, 0, stream>>>(cin, rowptr, se, ea_s, t, i, agg);
        mm1_k<<<NB1, 256, 0, stream>>>(agg, W1 + (size_t)i * H * H2, b1 + i * H2, y1, part);
        stats_k<<<1, 256, 0, stream>>>(part, NB1, stats);
        int nx = (i == NL - 1) ? 0 : (i + 1);  // next node-LN params (final uses layer 0's)
        mm2_k<<<NB1, 128, 0, stream>>>(y1, g1 + i * H2, bt1 + i * H2,
                                       W2 + (size_t)i * H2 * H, b2 + i * H, stats, h,
                                       lng + nx * H, lnb + nx * H, r, (i == 0) ? 1 : 0);
    }
    mmout_k<<<NB1, 128, 0, stream>>>(r, Wout, bout, out);
}

// Round 4
// 651.202 us; speedup vs baseline: 1.0391x; 1.0391x over previous
//
#include <hip/hip_runtime.h>
#include <math.h>

#define NN 10000
#define NE 640000
#define H 128
#define H2 256
#define XD 8
#define ED 8
#define YD 112
#define NL 4
#define EPS_MSG 1e-7f
#define EPS_SM 1e-16f
#define EPS_LN 1e-5f
#define TN 16
#define SLOTS 16

// ---------- CSR build ----------
__global__ void hist_k(const int* __restrict__ dst, int* __restrict__ counts) {
    int e = blockIdx.x * 256 + threadIdx.x;
    if (e < NE) atomicAdd(&counts[dst[e]], 1);
}

__global__ void scan_k(const int* __restrict__ counts, int* __restrict__ rowptr) {
    __shared__ int part[1024];
    int tid = threadIdx.x;
    const int CH = (NN + 1023) / 1024;  // 10
    int base = tid * CH;
    int s = 0;
    for (int j = 0; j < CH; j++) { int i = base + j; if (i < NN) s += counts[i]; }
    part[tid] = s; __syncthreads();
    for (int off = 1; off < 1024; off <<= 1) {
        int v = (tid >= off) ? part[tid - off] : 0;
        __syncthreads();
        part[tid] += v;
        __syncthreads();
    }
    int run = part[tid] - s;  // exclusive prefix
    for (int j = 0; j < CH; j++) {
        int i = base + j;
        if (i < NN) { rowptr[i] = run; run += counts[i]; }
    }
    if (tid == 1023) rowptr[NN] = run;  // == NE
}

__global__ void scatter_k(const int* __restrict__ src, const int* __restrict__ dst,
                          const float* __restrict__ eattr, const int* __restrict__ rowptr,
                          int* __restrict__ fill, int* __restrict__ srcs,
                          float* __restrict__ eacsr) {
    int e = blockIdx.x * 256 + threadIdx.x;
    if (e >= NE) return;
    int d = dst[e];
    int pos = rowptr[d] + atomicAdd(&fill[d], 1);
    srcs[pos] = src[e];
    const float4* ein = (const float4*)eattr;
    float4* eout = (float4*)eacsr;
    eout[(size_t)pos * 2]     = ein[(size_t)e * 2];
    eout[(size_t)pos * 2 + 1] = ein[(size_t)e * 2 + 1];
}

// ---------- node encoder: h = x @ Wn + bn ----------
__global__ void node_enc_k(const float* __restrict__ x, const float* __restrict__ Wn,
                           const float* __restrict__ bn, float* __restrict__ h) {
    int n = blockIdx.x, c = threadIdx.x;
    __shared__ float xl[XD];
    if (c < XD) xl[c] = x[n * XD + c];
    __syncthreads();
    float acc = bn[c];
#pragma unroll
    for (int k = 0; k < XD; k++) acc = fmaf(xl[k], Wn[k * H + c], acc);
    h[(size_t)n * H + c] = acc;
}

// ---------- per-node edge aggregation: 16 edge-slots x 16 ch-groups x 8 ch ----------
__global__ void __launch_bounds__(256) edge_agg_k(
    const float* __restrict__ rin, const int* __restrict__ rowptr,
    const int* __restrict__ srcs, const float* __restrict__ eacsr,
    const float* __restrict__ We, const float* __restrict__ be,
    const float* __restrict__ tptr, int layer, float* __restrict__ agg) {
    int n = blockIdx.x;
    int tid = threadIdx.x;
    int slot = tid >> 4;      // 0..15
    int g = tid & 15;         // channel group
    int c0 = g * 8;
    // We columns c0..c0+7 for all 8 k's, plus be slice: 64+8 regs
    float wc[ED][8];
    float bev[8];
#pragma unroll
    for (int k = 0; k < ED; k++) {
        float4 a = *(const float4*)(We + k * H + c0);
        float4 b = *(const float4*)(We + k * H + c0 + 4);
        wc[k][0] = a.x; wc[k][1] = a.y; wc[k][2] = a.z; wc[k][3] = a.w;
        wc[k][4] = b.x; wc[k][5] = b.y; wc[k][6] = b.z; wc[k][7] = b.w;
    }
    {
        float4 a = *(const float4*)(be + c0);
        float4 b = *(const float4*)(be + c0 + 4);
        bev[0] = a.x; bev[1] = a.y; bev[2] = a.z; bev[3] = a.w;
        bev[4] = b.x; bev[5] = b.y; bev[6] = b.z; bev[7] = b.w;
    }
    float ts2 = tptr[layer] * 1.44269504088896f;  // t * log2(e)
    float den[8], num[8];
#pragma unroll
    for (int i = 0; i < 8; i++) { den[i] = 0.f; num[i] = 0.f; }

    int beg = rowptr[n], end = rowptr[n + 1];
    for (int j = beg + slot; j < end; j += SLOTS) {
        int sn = srcs[j];
        float4 e0 = *(const float4*)(eacsr + (size_t)j * ED);
        float4 e1 = *(const float4*)(eacsr + (size_t)j * ED + 4);
        const float* hp = rin + (size_t)sn * H + c0;
        float4 h0 = *(const float4*)hp;
        float4 h1 = *(const float4*)(hp + 4);
        float er[8] = {e0.x, e0.y, e0.z, e0.w, e1.x, e1.y, e1.z, e1.w};
        float hv[8] = {h0.x, h0.y, h0.z, h0.w, h1.x, h1.y, h1.z, h1.w};
#pragma unroll
        for (int i = 0; i < 8; i++) {
            float p = bev[i];
#pragma unroll
            for (int k = 0; k < ED; k++) p = fmaf(er[k], wc[k][i], p);
            float msg = fmaxf(hv[i] + p, 0.f) + EPS_MSG;
            float pe = __builtin_amdgcn_exp2f(msg * ts2);
            den[i] += pe;                 // per-channel denominator
            num[i] = fmaf(pe, msg, num[i]);
        }
    }
    // reduce over the 4 slots within each wave (lanes l, l^16, l^32, l^48 share g)
#pragma unroll
    for (int off = 16; off <= 32; off <<= 1) {
#pragma unroll
        for (int i = 0; i < 8; i++) {
            den[i] += __shfl_xor(den[i], off);
            num[i] += __shfl_xor(num[i], off);
        }
    }
    __shared__ float red[4][16][16];
    int w = tid >> 6;
    if ((tid & 63) < 16) {
        int gg = tid & 15;
#pragma unroll
        for (int i = 0; i < 8; i++) {
            red[w][gg][i]     = den[i];
            red[w][gg][8 + i] = num[i];
        }
    }
    __syncthreads();
    if (tid < H) {
        int c = tid, gg = c >> 3, ii = c & 7;
        float D  = red[0][gg][ii]     + red[1][gg][ii]     + red[2][gg][ii]     + red[3][gg][ii];
        float Nu = red[0][gg][8 + ii] + red[1][gg][8 + ii] + red[2][gg][8 + ii] + red[3][gg][8 + ii];
        agg[(size_t)n * H + c] = Nu / (D + EPS_SM) + rin[(size_t)n * H + c];
    }
}

// ---------- y1 = agg @ W1[i] + b1[i], plus deterministic partial sums ----------
__global__ void __launch_bounds__(256) mm1_k(const float* __restrict__ agg,
    const float* __restrict__ W1i, const float* __restrict__ b1i,
    float* __restrict__ y1, float* __restrict__ part) {
    int nb = blockIdx.x, o = threadIdx.x;
    int n0 = nb * TN;
    __shared__ float a[TN][H];
    for (int t = o; t < TN * H; t += 256) ((float*)a)[t] = agg[(size_t)n0 * H + t];
    __syncthreads();
    float acc[TN];
#pragma unroll
    for (int i = 0; i < TN; i++) acc[i] = 0.f;
    for (int k = 0; k < H; k++) {
        float w = W1i[k * H2 + o];
#pragma unroll
        for (int i = 0; i < TN; i++) acc[i] = fmaf(a[i][k], w, acc[i]);
    }
    float bo = b1i[o];
    float ps = 0.f, ps2 = 0.f;
#pragma unroll
    for (int i = 0; i < TN; i++) {
        float v = acc[i] + bo;
        y1[(size_t)(n0 + i) * H2 + o] = v;
        ps += v; ps2 += v * v;
    }
#pragma unroll
    for (int off = 32; off; off >>= 1) { ps += __shfl_xor(ps, off); ps2 += __shfl_xor(ps2, off); }
    __shared__ float red[8];
    int w = o >> 6;
    if ((o & 63) == 0) { red[w] = ps; red[4 + w] = ps2; }
    __syncthreads();
    if (o == 0) {
        part[nb * 2]     = red[0] + red[1] + red[2] + red[3];
        part[nb * 2 + 1] = red[4] + red[5] + red[6] + red[7];
    }
}

// ---------- graph-LN stats finalize ----------
__global__ void stats_k(const float* __restrict__ part, int nb, float* __restrict__ stats) {
    int tid = threadIdx.x;  // 256
    float s = 0.f, s2 = 0.f;
    for (int i = tid; i < nb; i += 256) { s += part[2 * i]; s2 += part[2 * i + 1]; }
#pragma unroll
    for (int off = 32; off; off >>= 1) { s += __shfl_xor(s, off); s2 += __shfl_xor(s2, off); }
    __shared__ float red[8];
    int w = tid >> 6;
    if ((tid & 63) == 0) { red[w] = s; red[4 + w] = s2; }
    __syncthreads();
    if (tid == 0) {
        float S = red[0] + red[1] + red[2] + red[3];
        float S2 = red[4] + red[5] + red[6] + red[7];
        const float M = (float)NN * (float)H2;
        float m = S / M;
        float var = fmaxf(S2 / M - m * m, 0.f);
        stats[0] = m;
        stats[1] = 1.f / (sqrtf(var) + EPS_LN);
    }
}

// ---------- z = relu(graph_ln(y1)); h (+)= z @ W2[i] + b2[i]; r = relu(node_ln(h)) ----------
__global__ void __launch_bounds__(128) mm2_k(const float* __restrict__ y1,
    const float* __restrict__ g1i, const float* __restrict__ bt1i,
    const float* __restrict__ W2i, const float* __restrict__ b2i,
    const float* __restrict__ stats, float* __restrict__ h,
    const float* __restrict__ lgp, const float* __restrict__ lbp,
    float* __restrict__ r, int first) {
    int nb = blockIdx.x, o = threadIdx.x;
    int n0 = nb * TN;
    __shared__ float z[TN][H2];  // 16 KiB
    float m = stats[0], istd = stats[1];
    for (int t = o; t < TN * H2; t += 128) {
        int k = t & 255;
        float v = y1[(size_t)n0 * H2 + t];
        v = (v - m) * istd * g1i[k] + bt1i[k];
        ((float*)z)[t] = fmaxf(v, 0.f);
    }
    __syncthreads();
    float acc[TN];
#pragma unroll
    for (int i = 0; i < TN; i++) acc[i] = 0.f;
    for (int k = 0; k < H2; k++) {
        float w = W2i[k * H + o];
#pragma unroll
        for (int i = 0; i < TN; i++) acc[i] = fmaf(z[i][k], w, acc[i]);
    }
    float bo = b2i[o];
    float vv[TN];
#pragma unroll
    for (int i = 0; i < TN; i++) {
        size_t idx = (size_t)(n0 + i) * H + o;
        float v = acc[i] + bo;
        if (!first) v += h[idx];
        h[idx] = v;
        vv[i] = v;
    }
    // fused node-LN + ReLU -> r
    __shared__ float rs[2][TN], rs2[2][TN];
    int w = o >> 6;
#pragma unroll
    for (int i = 0; i < TN; i++) {
        float s = vv[i], s2 = vv[i] * vv[i];
#pragma unroll
        for (int off = 32; off; off >>= 1) { s += __shfl_xor(s, off); s2 += __shfl_xor(s2, off); }
        if ((o & 63) == 0) { rs[w][i] = s; rs2[w][i] = s2; }
    }
    __syncthreads();
    float gc = lgp[o], bc = lbp[o];
#pragma unroll
    for (int i = 0; i < TN; i++) {
        float S = rs[0][i] + rs[1][i], S2 = rs2[0][i] + rs2[1][i];
        float mn = S * (1.f / H);
        float var = S2 * (1.f / H) - mn * mn;
        float inv = rsqrtf(var + EPS_LN);
        float ov = (vv[i] - mn) * inv * gc + bc;
        r[(size_t)(n0 + i) * H + o] = fmaxf(ov, 0.f);
    }
}

// ---------- out = r @ Wout + bout ----------
__global__ void __launch_bounds__(128) mmout_k(const float* __restrict__ r,
    const float* __restrict__ Wout, const float* __restrict__ bout,
    float* __restrict__ out) {
    int nb = blockIdx.x, o = threadIdx.x;
    int n0 = nb * TN;
    __shared__ float a[TN][H];
    for (int t = o; t < TN * H; t += 128) ((float*)a)[t] = r[(size_t)n0 * H + t];
    __syncthreads();
    if (o < YD) {
        float acc[TN];
#pragma unroll
        for (int i = 0; i < TN; i++) acc[i] = 0.f;
        for (int k = 0; k < H; k++) {
            float w = Wout[k * YD + o];
#pragma unroll
            for (int i = 0; i < TN; i++) acc[i] = fmaf(a[i][k], w, acc[i]);
        }
        float bo = bout[o];
#pragma unroll
        for (int i = 0; i < TN; i++) out[(size_t)(n0 + i) * YD + o] = acc[i] + bo;
    }
}

extern "C" void kernel_launch(void* const* d_in, const int* in_sizes, int n_in,
                              void* d_out, int out_size, void* d_ws, size_t ws_size,
                              hipStream_t stream) {
    const float* x    = (const float*)d_in[0];
    const int*   ei   = (const int*)d_in[1];
    const float* eattr= (const float*)d_in[2];
    const float* Wn   = (const float*)d_in[3];
    const float* bn   = (const float*)d_in[4];
    const float* We   = (const float*)d_in[5];
    const float* be   = (const float*)d_in[6];
    const float* t    = (const float*)d_in[7];
    const float* W1   = (const float*)d_in[8];
    const float* b1   = (const float*)d_in[9];
    const float* g1   = (const float*)d_in[10];
    const float* bt1  = (const float*)d_in[11];
    const float* W2   = (const float*)d_in[12];
    const float* b2   = (const float*)d_in[13];
    const float* lng  = (const float*)d_in[14];
    const float* lnb  = (const float*)d_in[15];
    const float* Wout = (const float*)d_in[16];
    const float* bout = (const float*)d_in[17];
    float* out = (float*)d_out;

    const int* src = ei;        // edge_index[0]
    const int* dst = ei + NE;   // edge_index[1]

    char* ws = (char*)d_ws;
    size_t off = 0;
    auto alloc = [&](size_t bytes) -> char* {
        char* p = ws + off;
        off += (bytes + 255) & ~(size_t)255;
        return p;
    };
    int*   counts = (int*)alloc((size_t)NN * 4);
    int*   fill   = (int*)alloc((size_t)NN * 4);
    int*   rowptr = (int*)alloc((size_t)(NN + 1) * 4);
    int*   srcs   = (int*)alloc((size_t)NE * 4);
    float* eacsr  = (float*)alloc((size_t)NE * ED * 4);  // 20 MB
    float* h      = (float*)alloc((size_t)NN * H * 4);
    float* r      = (float*)alloc((size_t)NN * H * 4);
    float* agg    = (float*)alloc((size_t)NN * H * 4);
    float* y1     = (float*)alloc((size_t)NN * H2 * 4);
    const int NB1 = NN / TN;  // 625 (exact)
    float* part   = (float*)alloc((size_t)NB1 * 2 * 4);
    float* stats  = (float*)alloc(2 * 4);
    (void)ws_size; (void)in_sizes; (void)n_in; (void)out_size;

    hipMemsetAsync(counts, 0, (size_t)NN * 4, stream);
    hipMemsetAsync(fill,   0, (size_t)NN * 4, stream);

    hist_k<<<(NE + 255) / 256, 256, 0, stream>>>(dst, counts);
    scan_k<<<1, 1024, 0, stream>>>(counts, rowptr);
    scatter_k<<<(NE + 255) / 256, 256, 0, stream>>>(src, dst, eattr, rowptr, fill, srcs, eacsr);
    node_enc_k<<<NN, H, 0, stream>>>(x, Wn, bn, h);

    for (int i = 0; i < NL; i++) {
        const float* cin = (i == 0) ? h : r;
        edge_agg_k<<<NN, 256, 0, stream>>>(cin, rowptr, srcs, eacsr, We, be, t, i, agg);
        mm1_k<<<NB1, 256, 0, stream>>>(agg, W1 + (size_t)i * H * H2, b1 + i * H2, y1, part);
        stats_k<<<1, 256, 0, stream>>>(part, NB1, stats);
        int nx = (i == NL - 1) ? 0 : (i + 1);  // next node-LN params (final uses layer 0's)
        mm2_k<<<NB1, 128, 0, stream>>>(y1, g1 + i * H2, bt1 + i * H2,
                                       W2 + (size_t)i * H2 * H, b2 + i * H, stats, h,
                                       lng + nx * H, lnb + nx * H, r, (i == 0) ? 1 : 0);
    }
    mmout_k<<<NB1, 128, 0, stream>>>(r, Wout, bout, out);
}